// Round 1
// baseline (269.130 us; speedup 1.0000x reference)
//
#include <hip/hip_runtime.h>

#define NETS 32
#define BATCH 4096
#define D0 256
#define D1 512
#define D2 512
#define D3 128
#define MT 64            // batch rows per block
#define LDA (D0 + 8)     // 264 halves -> 528 B row stride (4-bank rotation per row)
#define LDH (D1 + 8)     // 520 halves -> 1040 B row stride

using half8 = __attribute__((ext_vector_type(8))) _Float16;
using half4 = __attribute__((ext_vector_type(4))) _Float16;
using f32x4 = __attribute__((ext_vector_type(4))) float;

#define W1_N (NETS * D1 * D0)   // 4,194,304
#define W2_N (NETS * D2 * D1)   // 8,388,608
#define W3_N (NETS * D3 * D2)   // 2,097,152

// ---------------- fp32 -> fp16 cast + fragment swizzle ----------------
// Swizzled layout: fragment f = ((net*4 + w)*NF + kk*NI + ni), 512 halves each.
// Within a fragment, lane l (l = quad*16 + lane16) owns halves [l*8, l*8+8) =
// source W[net][w*NWCH + ni*16 + lane16][kk*32 + quad*8 .. +8).
// => every wave B-load in the main kernel is one contiguous 1-KB transaction.
__global__ void cvt_weights(const float* __restrict__ W1, const float* __restrict__ W2,
                            const float* __restrict__ W3,
                            _Float16* __restrict__ W1h, _Float16* __restrict__ W2h,
                            _Float16* __restrict__ W3h) {
    const int i = blockIdx.x * blockDim.x + threadIdx.x;   // one 16-B frag-slice per thread
    constexpr int T1 = W1_N / 8, T2 = W2_N / 8, T3 = W3_N / 8;
    const float* src;
    _Float16* dst;
    if (i < T1) {
        // L1: K=256, NI=8, NF=64, n-chunk 128/wave
        int u = i, l = u & 63, f = u >> 6;
        int kkni = f & 63, netw = f >> 6;
        int ni = kkni & 7, kk = kkni >> 3;
        int net = netw >> 2, w = netw & 3;
        int n = w * 128 + ni * 16 + (l & 15);
        int k = kk * 32 + (l >> 4) * 8;
        src = W1 + (size_t)net * D1 * D0 + (size_t)n * D0 + k;
        dst = W1h + (size_t)f * 512 + l * 8;
    } else if (i < T1 + T2) {
        // L2: K=512, NI=8, NF=128
        int u = i - T1, l = u & 63, f = u >> 6;
        int kkni = f & 127, netw = f >> 7;
        int ni = kkni & 7, kk = kkni >> 3;
        int net = netw >> 2, w = netw & 3;
        int n = w * 128 + ni * 16 + (l & 15);
        int k = kk * 32 + (l >> 4) * 8;
        src = W2 + (size_t)net * D2 * D1 + (size_t)n * D1 + k;
        dst = W2h + (size_t)f * 512 + l * 8;
    } else {
        // L3: K=512, NI=2, NF=32, n-chunk 32/wave
        int u = i - T1 - T2, l = u & 63, f = u >> 6;
        int kkni = f & 31, netw = f >> 5;
        int ni = kkni & 1, kk = kkni >> 1;
        int net = netw >> 2, w = netw & 3;
        int n = w * 32 + ni * 16 + (l & 15);
        int k = kk * 32 + (l >> 4) * 8;
        src = W3 + (size_t)net * D3 * D2 + (size_t)n * D2 + k;
        dst = W3h + (size_t)f * 512 + l * 8;
    }
    float4 v0 = *reinterpret_cast<const float4*>(src);
    float4 v1 = *reinterpret_cast<const float4*>(src + 4);
    half8 o;
    o[0] = (_Float16)v0.x; o[1] = (_Float16)v0.y; o[2] = (_Float16)v0.z; o[3] = (_Float16)v0.w;
    o[4] = (_Float16)v1.x; o[5] = (_Float16)v1.y; o[6] = (_Float16)v1.z; o[7] = (_Float16)v1.w;
    *reinterpret_cast<half8*>(dst) = o;
}

// ---------------- deep-pipelined layer, coalesced B stream ----------------
// B (weights) streamed from L2 with a DEPTH-group modulo ring: loads for step
// s+DEPTH issue at step s => (DEPTH-1)*~78cy coverage > 200cy L2 latency.
// A (activations) ds_read with an ADEPTH-kk ring, prefetched at kk start.
// MFMA operands are SWAPPED (W as A-operand, act as B-operand): both operand
// fragments have identical lane layouts for 16x16x32, and the swap transposes
// C so that lane16 indexes m and quad*4+r indexes n -> each lane's 4 acc
// values are contiguous along n (vectorized epilogue).
template<int K, int NI, int G, int MI, int DEPTH, int ADEPTH>
__device__ __forceinline__ void layer_mfma(const _Float16* As, int lda,
                                           const _Float16* __restrict__ wl,
                                           int lane16, int quad,
                                           f32x4 (&acc)[MI][NI]) {
    constexpr int KK = K / 32;
    constexpr int NFR = KK * NI;
    constexpr int STEPS = NFR / G;
    static_assert(STEPS >= DEPTH, "prefetch ring deeper than steps");
    half8 b[DEPTH][G];
    half8 a[ADEPTH][MI];
    // B prologue: fill the ring
#pragma unroll
    for (int d = 0; d < DEPTH; ++d)
#pragma unroll
        for (int g = 0; g < G; ++g)
            b[d][g] = *reinterpret_cast<const half8*>(wl + (size_t)(d * G + g) * 512);
    // A prologue: kk = 0 .. ADEPTH-2
#pragma unroll
    for (int j = 0; j < ADEPTH - 1; ++j)
#pragma unroll
        for (int mi = 0; mi < MI; ++mi)
            a[j][mi] = *reinterpret_cast<const half8*>(
                As + (mi * 16 + lane16) * lda + j * 32 + quad * 8);
#pragma unroll
    for (int s = 0; s < STEPS; ++s) {
        const int cur = s % DEPTH;
        const int fb = s * G;
        // A prefetch: at each kk boundary, fetch kk+ADEPTH-1
        if (fb % NI == 0) {
            const int kk = fb / NI;
            const int pk = kk + ADEPTH - 1;
            if (pk < KK) {
#pragma unroll
                for (int mi = 0; mi < MI; ++mi)
                    a[pk % ADEPTH][mi] = *reinterpret_cast<const half8*>(
                        As + (mi * 16 + lane16) * lda + pk * 32 + quad * 8);
            }
        }
#pragma unroll
        for (int g = 0; g < G; ++g) {
            const int f = fb + g;
            const int ni = f % NI;
            const int ka = (f / NI) % ADEPTH;
#pragma unroll
            for (int mi = 0; mi < MI; ++mi)
                acc[mi][ni] = __builtin_amdgcn_mfma_f32_16x16x32_f16(
                    b[cur][g], a[ka][mi], acc[mi][ni], 0, 0, 0);
        }
        // B prefetch for step s+DEPTH into the slot just consumed
        if (s + DEPTH < STEPS) {
#pragma unroll
            for (int g = 0; g < G; ++g)
                b[cur][g] = *reinterpret_cast<const half8*>(
                    wl + (size_t)((s + DEPTH) * G + g) * 512);
        }
    }
}

// Swapped-C layout: acc[mi][ni][r] = H[mi*16 + lane16][ni*16 + quad*4 + r].
// 4 contiguous n per lane -> one ds_write_b64 per (mi,ni), float4 bias load.
template<int MI, int NI>
__device__ __forceinline__ void store_act(f32x4 (&acc)[MI][NI], const float* __restrict__ bias,
                                          _Float16* dst, int ldd, int n_base,
                                          int lane16, int quad) {
#pragma unroll
    for (int ni = 0; ni < NI; ++ni) {
        const int n0 = n_base + ni * 16 + quad * 4;
        const float4 bv = *reinterpret_cast<const float4*>(bias + n0);
#pragma unroll
        for (int mi = 0; mi < MI; ++mi) {
            half4 o;
            o[0] = (_Float16)fmaxf(acc[mi][ni][0] + bv.x, 0.0f);
            o[1] = (_Float16)fmaxf(acc[mi][ni][1] + bv.y, 0.0f);
            o[2] = (_Float16)fmaxf(acc[mi][ni][2] + bv.z, 0.0f);
            o[3] = (_Float16)fmaxf(acc[mi][ni][3] + bv.w, 0.0f);
            *reinterpret_cast<half4*>(&dst[(mi * 16 + lane16) * ldd + n0]) = o;
        }
    }
}

// ---------------- fused 3-layer MLP, single in-place LDS buffer ----------------
__global__ __launch_bounds__(256, 2) void mlp_fused(
    const float* __restrict__ X,
    const _Float16* __restrict__ W1h, const float* __restrict__ b1,
    const _Float16* __restrict__ W2h, const float* __restrict__ b2,
    const _Float16* __restrict__ W3h, const float* __restrict__ b3,
    float* __restrict__ out) {
    __shared__ __align__(16) _Float16 buf[MT * LDH];   // X (LDA layout) -> H1 -> H2 (LDH)

    const int tid = threadIdx.x;
    const int w = tid >> 6;
    const int l = tid & 63;
    const int lane16 = l & 15;
    const int quad = l >> 4;

    // XCD-locality: dispatch round-robins blockIdx over 8 XCDs -> 4 nets/XCD
    // (3.7 MB fp16 weights per XCD-L2).
    const int bb = blockIdx.x;            // 0..2047
    const int xcd = bb & 7;
    const int s = bb >> 3;                // 0..255
    const int net = xcd * 4 + (s >> 6);   // 0..31
    const int mt = s & 63;                // 0..63
    const int m0 = mt * MT;

    // ---- stage X tile [MT][D0] fp32 -> fp16 into buf (LDA layout) ----
    // MT*D0/4 = 4096 float4 chunks; 256 threads x 16 iters.
    {
        const float* xsrc = X + (size_t)m0 * D0;
#pragma unroll
        for (int it = 0; it < 16; ++it) {
            int chunk = it * 256 + tid;   // 0..4095; 64 float4 per row
            int row = chunk >> 6;
            int c4 = chunk & 63;
            float4 v = *reinterpret_cast<const float4*>(xsrc + row * D0 + c4 * 4);
            half4 o;
            o[0] = (_Float16)v.x; o[1] = (_Float16)v.y;
            o[2] = (_Float16)v.z; o[3] = (_Float16)v.w;
            *reinterpret_cast<half4*>(&buf[row * LDA + c4 * 4]) = o;
        }
    }
    __syncthreads();

    // ---- layer 1: H1 = relu(X @ W1^T + b1), K=256, N=512 (wave owns 128 cols) ----
    {
        f32x4 acc[4][8] = {};
        const _Float16* wl = W1h + ((size_t)(net * 4 + w) * 64) * 512 + l * 8;
        layer_mfma<D0, 8, 4, 4, 4, 2>(buf, LDA, wl, lane16, quad, acc);
        __syncthreads();                               // all X reads done
        store_act<4, 8>(acc, b1 + net * D1, buf, LDH, w * 128, lane16, quad);
    }
    __syncthreads();

    // ---- layer 2: H2 = relu(H1 @ W2^T + b2), K=512, N=512 ----
    {
        f32x4 acc[4][8] = {};
        const _Float16* wl = W2h + ((size_t)(net * 4 + w) * 128) * 512 + l * 8;
        layer_mfma<D1, 8, 4, 4, 4, 2>(buf, LDH, wl, lane16, quad, acc);
        __syncthreads();                               // all H1 reads done
        store_act<4, 8>(acc, b2 + net * D2, buf, LDH, w * 128, lane16, quad);
    }
    __syncthreads();

    // ---- layer 3: out = H2 @ W3^T + b3, K=512, N=128 (wave owns 32 cols) ----
    {
        f32x4 acc[4][2] = {};
        const _Float16* wl = W3h + ((size_t)(net * 4 + w) * 32) * 512 + l * 8;
        layer_mfma<D2, 2, 2, 4, 6, 4>(buf, LDH, wl, lane16, quad, acc);
        const int n_base = w * 32;
#pragma unroll
        for (int ni = 0; ni < 2; ++ni) {
            const int n0 = n_base + ni * 16 + quad * 4;
            const float4 bv = *reinterpret_cast<const float4*>(b3 + net * D3 + n0);
#pragma unroll
            for (int mi = 0; mi < 4; ++mi) {
                const int row = m0 + mi * 16 + lane16;
                float4 v;
                v.x = acc[mi][ni][0] + bv.x;
                v.y = acc[mi][ni][1] + bv.y;
                v.z = acc[mi][ni][2] + bv.z;
                v.w = acc[mi][ni][3] + bv.w;
                *reinterpret_cast<float4*>(
                    &out[(size_t)row * (NETS * D3) + net * D3 + n0]) = v;
            }
        }
    }
}

extern "C" void kernel_launch(void* const* d_in, const int* in_sizes, int n_in,
                              void* d_out, int out_size, void* d_ws, size_t ws_size,
                              hipStream_t stream) {
    const float* x  = (const float*)d_in[0];
    const float* W1 = (const float*)d_in[1];
    const float* b1 = (const float*)d_in[2];
    const float* W2 = (const float*)d_in[3];
    const float* b2 = (const float*)d_in[4];
    const float* W3 = (const float*)d_in[5];
    const float* b3 = (const float*)d_in[6];
    float* out = (float*)d_out;

    // ws layout (fp16, swizzled): W1h | W2h | W3h  = ~29.4 MB total
    _Float16* W1h = (_Float16*)d_ws;
    _Float16* W2h = W1h + (size_t)W1_N;
    _Float16* W3h = W2h + (size_t)W2_N;

    const int totalT = (W1_N + W2_N + W3_N) / 8;       // 1,835,008 threads
    cvt_weights<<<totalT / 256, 256, 0, stream>>>(W1, W2, W3, W1h, W2h, W3h);

    mlp_fused<<<NETS * (BATCH / MT), 256, 0, stream>>>(x, W1h, b1, W2h, b2, W3h, b3, out);
}

// Round 3
// 257.702 us; speedup vs baseline: 1.0443x; 1.0443x over previous
//
#include <hip/hip_runtime.h>

#define NETS 32
#define BATCH 4096
#define D0 256
#define D1 512
#define D2 512
#define D3 128
#define MT 64            // batch rows per block
#define LDA (D0 + 8)     // 264 halves -> 528 B row stride (4-bank rotation per row)
#define LDH (D1 + 8)     // 520 halves -> 1040 B row stride

using half8 = __attribute__((ext_vector_type(8))) _Float16;
using half4 = __attribute__((ext_vector_type(4))) _Float16;
using f32x4 = __attribute__((ext_vector_type(4))) float;

#define W1_N (NETS * D1 * D0)   // 4,194,304
#define W2_N (NETS * D2 * D1)   // 8,388,608
#define W3_N (NETS * D3 * D2)   // 2,097,152

// ---------------- fp32 -> fp16 cast + fragment swizzle ----------------
// Swizzled layout: fragment f = ((net*4 + w)*NF + kk*NI + ni), 512 halves each.
// Within a fragment, lane l (l = quad*16 + lane16) owns halves [l*8, l*8+8) =
// source W[net][w*NWCH + ni*16 + lane16][kk*32 + quad*8 .. +8).
// => every wave B-load in the main kernel is one contiguous 1-KB transaction.
// Source reads are single-use -> nontemporal (don't displace anything useful).
__global__ void cvt_weights(const float* __restrict__ W1, const float* __restrict__ W2,
                            const float* __restrict__ W3,
                            _Float16* __restrict__ W1h, _Float16* __restrict__ W2h,
                            _Float16* __restrict__ W3h) {
    const int i = blockIdx.x * blockDim.x + threadIdx.x;   // one 16-B frag-slice per thread
    constexpr int T1 = W1_N / 8, T2 = W2_N / 8, T3 = W3_N / 8;
    const float* src;
    _Float16* dst;
    if (i < T1) {
        // L1: K=256, NI=8, NF=64, n-chunk 128/wave
        int u = i, l = u & 63, f = u >> 6;
        int kkni = f & 63, netw = f >> 6;
        int ni = kkni & 7, kk = kkni >> 3;
        int net = netw >> 2, w = netw & 3;
        int n = w * 128 + ni * 16 + (l & 15);
        int k = kk * 32 + (l >> 4) * 8;
        src = W1 + (size_t)net * D1 * D0 + (size_t)n * D0 + k;
        dst = W1h + (size_t)f * 512 + l * 8;
    } else if (i < T1 + T2) {
        // L2: K=512, NI=8, NF=128
        int u = i - T1, l = u & 63, f = u >> 6;
        int kkni = f & 127, netw = f >> 7;
        int ni = kkni & 7, kk = kkni >> 3;
        int net = netw >> 2, w = netw & 3;
        int n = w * 128 + ni * 16 + (l & 15);
        int k = kk * 32 + (l >> 4) * 8;
        src = W2 + (size_t)net * D2 * D1 + (size_t)n * D1 + k;
        dst = W2h + (size_t)f * 512 + l * 8;
    } else {
        // L3: K=512, NI=2, NF=32, n-chunk 32/wave
        int u = i - T1 - T2, l = u & 63, f = u >> 6;
        int kkni = f & 31, netw = f >> 5;
        int ni = kkni & 1, kk = kkni >> 1;
        int net = netw >> 2, w = netw & 3;
        int n = w * 32 + ni * 16 + (l & 15);
        int k = kk * 32 + (l >> 4) * 8;
        src = W3 + (size_t)net * D3 * D2 + (size_t)n * D2 + k;
        dst = W3h + (size_t)f * 512 + l * 8;
    }
    f32x4 v0 = __builtin_nontemporal_load(reinterpret_cast<const f32x4*>(src));
    f32x4 v1 = __builtin_nontemporal_load(reinterpret_cast<const f32x4*>(src) + 1);
    half8 o;
    o[0] = (_Float16)v0[0]; o[1] = (_Float16)v0[1]; o[2] = (_Float16)v0[2]; o[3] = (_Float16)v0[3];
    o[4] = (_Float16)v1[0]; o[5] = (_Float16)v1[1]; o[6] = (_Float16)v1[2]; o[7] = (_Float16)v1[3];
    *reinterpret_cast<half8*>(dst) = o;
}

// ---------------- software-pipelined layer, coalesced B stream ----------------
// wl points at this (net,wave)'s first fragment + l*8. Fragments are consumed
// linearly: f = kk*NI + ni. Prefetch G fragments one group ahead.
// (Register budget note: acc[4][8]=128 AGPR + ~120 VGPR = 248/256 at 2 waves/SIMD.
//  Deeper register prefetch does NOT fit — measured regression in R1.)
template<int K, int NI, int G, int MI>
__device__ __forceinline__ void layer_mfma(const _Float16* As, int lda,
                                           const _Float16* __restrict__ wl,
                                           int lane16, int quad,
                                           f32x4 (&acc)[MI][NI]) {
    constexpr int NFR = (K / 32) * NI;
    constexpr int STEPS = NFR / G;
    half8 bcur[G], bnxt[G];
    half8 a[MI];
#pragma unroll
    for (int g = 0; g < G; ++g)
        bcur[g] = *reinterpret_cast<const half8*>(wl + (size_t)g * 512);
#pragma unroll
    for (int s = 0; s < STEPS; ++s) {
        const int fb = s * G;
        if (s + 1 < STEPS) {
#pragma unroll
            for (int g = 0; g < G; ++g)
                bnxt[g] = *reinterpret_cast<const half8*>(wl + (size_t)(fb + G + g) * 512);
        }
        if (fb % NI == 0) {
            const int kk = fb / NI;
#pragma unroll
            for (int mi = 0; mi < MI; ++mi)
                a[mi] = *reinterpret_cast<const half8*>(
                    As + (mi * 16 + lane16) * lda + kk * 32 + quad * 8);
        }
#pragma unroll
        for (int g = 0; g < G; ++g) {
            const int ni = (fb + g) % NI;
#pragma unroll
            for (int mi = 0; mi < MI; ++mi)
                acc[mi][ni] = __builtin_amdgcn_mfma_f32_16x16x32_f16(a[mi], bcur[g], acc[mi][ni], 0, 0, 0);
        }
        if (s + 1 < STEPS) {
#pragma unroll
            for (int g = 0; g < G; ++g) bcur[g] = bnxt[g];
        }
    }
}

template<int MI, int NI>
__device__ __forceinline__ void store_act(f32x4 (&acc)[MI][NI], const float* __restrict__ bias,
                                          _Float16* dst, int ldd, int n_base,
                                          int lane16, int quad) {
#pragma unroll
    for (int ni = 0; ni < NI; ++ni) {
        float bv = bias[n_base + ni * 16 + lane16];
        int col = n_base + ni * 16 + lane16;
#pragma unroll
        for (int mi = 0; mi < MI; ++mi) {
#pragma unroll
            for (int r = 0; r < 4; ++r) {
                float v = acc[mi][ni][r] + bv;
                v = fmaxf(v, 0.0f);                        // relu
                int row = mi * 16 + quad * 4 + r;
                dst[row * ldd + col] = (_Float16)v;
            }
        }
    }
}

// ---------------- fused 3-layer MLP, single in-place LDS buffer ----------------
__global__ __launch_bounds__(256, 2) void mlp_fused(
    const float* __restrict__ X,
    const _Float16* __restrict__ W1h, const float* __restrict__ b1,
    const _Float16* __restrict__ W2h, const float* __restrict__ b2,
    const _Float16* __restrict__ W3h, const float* __restrict__ b3,
    float* __restrict__ out) {
    __shared__ __align__(16) _Float16 buf[MT * LDH];   // X (LDA layout) -> H1 -> H2 (LDH)

    const int tid = threadIdx.x;
    const int w = tid >> 6;
    const int l = tid & 63;
    const int lane16 = l & 15;
    const int quad = l >> 4;

    // XCD-locality: dispatch round-robins blockIdx over 8 XCDs -> 4 nets/XCD.
    // Within a dispatch round, each XCD runs ONE net (0.92 MB fp16 weights),
    // reused by all 64 row-tiles -> must stay L2-resident. The streaming
    // traffic (X reads, out writes) is marked nontemporal so it cannot evict
    // the weight working set (R1 counters: 44 MB of excess HBM weight
    // re-fetch without this).
    const int bb = blockIdx.x;            // 0..2047
    const int xcd = bb & 7;
    const int s = bb >> 3;                // 0..255
    const int net = xcd * 4 + (s >> 6);   // 0..31
    const int mt = s & 63;                // 0..63
    const int m0 = mt * MT;

    // ---- stage X tile [MT][D0] fp32 -> fp16 into buf (LDA layout) ----
    // MT*D0/4 = 4096 float4 chunks; 256 threads x 16 iters. Nontemporal: each
    // block's X slice is read once; cross-net reuse is served by L3.
    {
        const float* xsrc = X + (size_t)m0 * D0;
#pragma unroll
        for (int it = 0; it < 16; ++it) {
            int chunk = it * 256 + tid;   // 0..4095; 64 float4 per row
            int row = chunk >> 6;
            int c4 = chunk & 63;
            f32x4 v = __builtin_nontemporal_load(
                reinterpret_cast<const f32x4*>(xsrc + row * D0 + c4 * 4));
            half4 o;
            o[0] = (_Float16)v[0]; o[1] = (_Float16)v[1];
            o[2] = (_Float16)v[2]; o[3] = (_Float16)v[3];
            *reinterpret_cast<half4*>(&buf[row * LDA + c4 * 4]) = o;
        }
    }
    __syncthreads();

    // ---- layer 1: H1 = relu(X @ W1^T + b1), K=256, N=512 (wave owns 128 cols) ----
    {
        f32x4 acc[4][8] = {};
        const _Float16* wl = W1h + ((size_t)(net * 4 + w) * 64) * 512 + l * 8;
        layer_mfma<D0, 8, 4, 4>(buf, LDA, wl, lane16, quad, acc);
        __syncthreads();                               // all X reads done
        store_act<4, 8>(acc, b1 + net * D1, buf, LDH, w * 128, lane16, quad);
    }
    __syncthreads();

    // ---- layer 2: H2 = relu(H1 @ W2^T + b2), K=512, N=512 ----
    {
        f32x4 acc[4][8] = {};
        const _Float16* wl = W2h + ((size_t)(net * 4 + w) * 128) * 512 + l * 8;
        layer_mfma<D1, 8, 4, 4>(buf, LDH, wl, lane16, quad, acc);
        __syncthreads();                               // all H1 reads done
        store_act<4, 8>(acc, b2 + net * D2, buf, LDH, w * 128, lane16, quad);
    }
    __syncthreads();

    // ---- layer 3: out = H2 @ W3^T + b3, K=512, N=128 (wave owns 32 cols) ----
    {
        f32x4 acc[4][2] = {};
        const _Float16* wl = W3h + ((size_t)(net * 4 + w) * 32) * 512 + l * 8;
        layer_mfma<D2, 2, 2, 4>(buf, LDH, wl, lane16, quad, acc);
        const int n_base = w * 32;
#pragma unroll
        for (int ni = 0; ni < 2; ++ni) {
            float bv = b3[net * D3 + n_base + ni * 16 + lane16];
            int col = net * D3 + n_base + ni * 16 + lane16;
#pragma unroll
            for (int mi = 0; mi < 4; ++mi) {
#pragma unroll
                for (int r = 0; r < 4; ++r) {
                    int row = m0 + mi * 16 + quad * 4 + r;
                    // streaming, zero-reuse -> bypass L2 allocation
                    __builtin_nontemporal_store(acc[mi][ni][r] + bv,
                        &out[(size_t)row * (NETS * D3) + col]);
                }
            }
        }
    }
}

extern "C" void kernel_launch(void* const* d_in, const int* in_sizes, int n_in,
                              void* d_out, int out_size, void* d_ws, size_t ws_size,
                              hipStream_t stream) {
    const float* x  = (const float*)d_in[0];
    const float* W1 = (const float*)d_in[1];
    const float* b1 = (const float*)d_in[2];
    const float* W2 = (const float*)d_in[3];
    const float* b2 = (const float*)d_in[4];
    const float* W3 = (const float*)d_in[5];
    const float* b3 = (const float*)d_in[6];
    float* out = (float*)d_out;

    // ws layout (fp16, swizzled): W1h | W2h | W3h  = ~29.4 MB total
    _Float16* W1h = (_Float16*)d_ws;
    _Float16* W2h = W1h + (size_t)W1_N;
    _Float16* W3h = W2h + (size_t)W2_N;

    const int totalT = (W1_N + W2_N + W3_N) / 8;       // 1,835,008 threads
    cvt_weights<<<totalT / 256, 256, 0, stream>>>(W1, W2, W3, W1h, W2h, W3h);

    mlp_fused<<<NETS * (BATCH / MT), 256, 0, stream>>>(x, W1h, b1, W2h, b2, W3h, b3, out);
}